// Round 22
// baseline (206.725 us; speedup 1.0000x reference)
//
#include <hip/hip_runtime.h>

#define N_NODES 50000
#define D_NB 16
#define IN_DIM 256
#define OUT_DIM 128
#define K_HEADS 4
#define SLOPE 0.01f
#define BN 16           // nodes per fused block

typedef __attribute__((ext_vector_type(8))) short short8;
typedef __attribute__((ext_vector_type(4))) float f32x4;

static __device__ __forceinline__ unsigned f2bf(float f) {
    unsigned u = __float_as_uint(f);
    unsigned r = u + 0x7fffu + ((u >> 16) & 1u);   // RNE
    return r >> 16;
}
static __device__ __forceinline__ float bf2f(unsigned short b) {
    return __uint_as_float(((unsigned)b) << 16);
}

// ---------------- Kernel 0: Wb = bf16(W) [blocks 0..2047]; wt8 [blocks 2048..2055] ----------
__global__ __launch_bounds__(256) void prep_w_kernel(
    const float* __restrict__ W, const float* __restrict__ a,
    unsigned short* __restrict__ Wb, float* __restrict__ wt8)
{
    if (blockIdx.x < 2048) {
        const int id = blockIdx.x * 256 + threadIdx.x;
        Wb[id] = (unsigned short)f2bf(W[id]);
        return;
    }
    const int v = blockIdx.x - 2048;    // 0..7
    const int k = v >> 1, s = v & 1;
    const int i = threadIdx.x;          // 0..255
    const float* av = a + k * 2 * OUT_DIM + s * OUT_DIM;
    float acc = 0.f;
    #pragma unroll 4
    for (int o = 0; o < OUT_DIM; ++o)
        acc += W[((size_t)k * OUT_DIM + o) * IN_DIM + i] * av[o];
    wt8[v * IN_DIM + i] = acc;
}

// ---------------- Kernel 1: prep — Xb = bf16(X); e4 layouts [n][4] (heads adjacent) --------
__global__ __launch_bounds__(256) void prep_kernel(
    const float* __restrict__ X, const float* __restrict__ wt8,
    unsigned short* __restrict__ Xb, float* __restrict__ e_nb4, float* __restrict__ e_self4)
{
    const int t = threadIdx.x;
    const int w = t >> 6;
    const int lane = t & 63;
    const int n = blockIdx.x * 4 + w;

    const f32x4 x = __builtin_nontemporal_load(
        (const f32x4*)(X + (size_t)n * IN_DIM + lane * 4));
    uint2 pk;
    pk.x = f2bf(x[0]) | (f2bf(x[1]) << 16);
    pk.y = f2bf(x[2]) | (f2bf(x[3]) << 16);
    *(uint2*)(Xb + (size_t)n * IN_DIM + lane * 4) = pk;

    float p[8];
    #pragma unroll
    for (int v = 0; v < 8; ++v) {
        const float4 wv = *(const float4*)(wt8 + v * IN_DIM + lane * 4);
        p[v] = x[0] * wv.x + x[1] * wv.y + x[2] * wv.z + x[3] * wv.w;
    }
    #pragma unroll
    for (int sh = 32; sh >= 1; sh >>= 1) {
        #pragma unroll
        for (int v = 0; v < 8; ++v) p[v] += __shfl_xor(p[v], sh);
    }
    if (lane == 0) {
        *(float4*)(e_nb4 + (size_t)n * 4)   = float4{p[0], p[2], p[4], p[6]};
        *(float4*)(e_self4 + (size_t)n * 4) = float4{p[1], p[3], p[5], p[7]};
    }
}

// ---------------- Kernel 2: FUSED gather+softmax+aggregate+MFMA-projection ----------------
// 512 thr / 8 waves / 16 nodes per block.
// Phase 1 (gather): wave w handles nodes bn0+2w, bn0+2w+1 (r18's uint2 form, all 4 heads);
//   aggregated rows written bf16 to a 32KB LDS tile [head][node][256], XOR-swizzled
//   (^(row&7)<<4 on the byte offset) so phase-2 A-frag ds_read_b128 is conflict-free.
// Phase 2 (MFMA): wave w -> head h=w>>1, out-cols (w&1)*64..+63: 8 A-frags from LDS,
//   32 B-frags direct from L2-hot Wb (256KB), 32 MFMA, out stored directly.
// Eliminates the 102MB aggX LLC roundtrip and all gemm2 staging barriers.
__global__ __launch_bounds__(512) void fused_kernel(
    const int* __restrict__ nidx, const unsigned short* __restrict__ Xb,
    const float* __restrict__ e_nb4, const float* __restrict__ e_self4,
    const unsigned short* __restrict__ Wb, float* __restrict__ out)
{
    __shared__ unsigned short tile[K_HEADS * BN * IN_DIM];   // 32 KB

    const int t = threadIdx.x;
    const int w = t >> 6;          // 0..7
    const int lane = t & 63;
    const int bn0 = blockIdx.x * BN;

    const int k = lane >> 4;       // head for softmax phase
    const int dl = lane & 15;      // neighbor slot

    // ---- Phase 1: gather + softmax + aggregate, 2 nodes per wave ----
    #pragma unroll
    for (int half = 0; half < 2; ++half) {
        const int row = 2 * w + half;          // tile row 0..15
        const int n = bn0 + row;

        const int nbr = __builtin_nontemporal_load(nidx + (size_t)n * D_NB + dl);
        const float4 eb4 = *(const float4*)(e_nb4 + (size_t)nbr * 4);
        const float4 es4 = *(const float4*)(e_self4 + (size_t)n * 4);
        const float en = (k & 2) ? ((k & 1) ? eb4.w : eb4.z) : ((k & 1) ? eb4.y : eb4.x);
        const float es = (k & 2) ? ((k & 1) ? es4.w : es4.z) : ((k & 1) ? es4.y : es4.x);
        const float xv = en + es;
        const float v = xv > 0.f ? xv : SLOPE * xv;
        float m = v;
        #pragma unroll
        for (int sh = 8; sh >= 1; sh >>= 1) m = fmaxf(m, __shfl_xor(m, sh, 16));
        const float pz = __expf(v - m);
        float sum = pz;
        #pragma unroll
        for (int sh = 8; sh >= 1; sh >>= 1) sum += __shfl_xor(sum, sh, 16);
        const float alpha = pz / sum;

        float acc[4][4] = {};
        #pragma unroll
        for (int h2 = 0; h2 < 2; ++h2) {
            uint2 u[8];
            #pragma unroll
            for (int b = 0; b < 8; ++b) {
                const int nd = __shfl(nbr, h2 * 8 + b);
                u[b] = *(const uint2*)(Xb + (size_t)nd * IN_DIM + lane * 4);
            }
            #pragma unroll
            for (int b = 0; b < 8; ++b) {
                const float x0 = bf2f((unsigned short)(u[b].x & 0xffffu));
                const float x1 = bf2f((unsigned short)(u[b].x >> 16));
                const float x2 = bf2f((unsigned short)(u[b].y & 0xffffu));
                const float x3 = bf2f((unsigned short)(u[b].y >> 16));
                #pragma unroll
                for (int kk = 0; kk < 4; ++kk) {
                    const float ad = __shfl(alpha, kk * 16 + h2 * 8 + b);
                    acc[kk][0] += ad * x0;
                    acc[kk][1] += ad * x1;
                    acc[kk][2] += ad * x2;
                    acc[kk][3] += ad * x3;
                }
            }
        }
        // write aggregated row (bf16) to LDS tile, swizzled within the 512B row
        #pragma unroll
        for (int kk = 0; kk < 4; ++kk) {
            uint2 pk;
            pk.x = f2bf(acc[kk][0]) | (f2bf(acc[kk][1]) << 16);
            pk.y = f2bf(acc[kk][2]) | (f2bf(acc[kk][3]) << 16);
            const int boff = (kk * (BN * IN_DIM * 2) + row * (IN_DIM * 2) + lane * 8)
                             ^ ((row & 7) << 4);
            *(uint2*)((char*)tile + boff) = pk;
        }
    }
    __syncthreads();

    // ---- Phase 2: MFMA projection. wave w -> head h, 64 out-cols ----
    const int h = w >> 1;
    const int c4 = (w & 1) * 4;     // colfrag base (4 x 16 cols)
    const int lrow = lane & 15;     // node row
    const int lk = lane >> 4;       // k-chunk

    f32x4 acc2[4] = {};
    #pragma unroll
    for (int kk = 0; kk < 8; ++kk) {
        const int aoff = (h * (BN * IN_DIM * 2) + lrow * (IN_DIM * 2) + kk * 64 + lk * 16)
                         ^ ((lrow & 7) << 4);
        const short8 af = *(const short8*)((const char*)tile + aoff);
        #pragma unroll
        for (int c = 0; c < 4; ++c) {
            const int ocol = (c4 + c) * 16 + lrow;
            const short8 bf = *(const short8*)(
                Wb + ((size_t)h * OUT_DIM + ocol) * IN_DIM + kk * 32 + lk * 8);
            acc2[c] = __builtin_amdgcn_mfma_f32_16x16x32_bf16(bf, af, acc2[c], 0, 0, 0);
        }
    }
    #pragma unroll
    for (int c = 0; c < 4; ++c) {
        *(f32x4*)(out + (size_t)(bn0 + lrow) * (K_HEADS * OUT_DIM)
                  + h * OUT_DIM + (c4 + c) * 16 + lk * 4) = acc2[c];
    }
}

// ---------------- launch ----------------
extern "C" void kernel_launch(void* const* d_in, const int* in_sizes, int n_in,
                              void* d_out, int out_size, void* d_ws, size_t ws_size,
                              hipStream_t stream) {
    const float* X = (const float*)d_in[0];
    const float* W = (const float*)d_in[1];
    const float* a = (const float*)d_in[2];
    const int* nidx = (const int*)d_in[3];
    float* out = (float*)d_out;

    char* p = (char*)d_ws;
    unsigned short* Wb   = (unsigned short*)p;   p += (size_t)K_HEADS * OUT_DIM * IN_DIM * 2;
    unsigned short* Xb   = (unsigned short*)p;   p += (size_t)N_NODES * IN_DIM * 2;
    float*          wt8  = (float*)p;            p += (size_t)8 * IN_DIM * 4;
    float*          enb4 = (float*)p;            p += (size_t)K_HEADS * N_NODES * 4;
    float*          esf4 = (float*)p;

    hipLaunchKernelGGL(prep_w_kernel, dim3(2056), dim3(256), 0, stream, W, a, Wb, wt8);

    hipLaunchKernelGGL(prep_kernel,
        dim3(N_NODES / 4), dim3(256), 0, stream, X, wt8, Xb, enb4, esf4);

    hipLaunchKernelGGL(fused_kernel,
        dim3(N_NODES / BN), dim3(512), 0, stream, nidx, Xb, enb4, esf4, Wb, out);
}

// Round 23
// 155.841 us; speedup vs baseline: 1.3265x; 1.3265x over previous
//
#include <hip/hip_runtime.h>

#define N_NODES 50000
#define D_NB 16
#define IN_DIM 256
#define OUT_DIM 128
#define K_HEADS 4
#define SLOPE 0.01f
#define NSLICE 16       // GEMM2 stage s = k*4 + cb; 32 out-cols each
#define SLICE_COLS 32

typedef __attribute__((ext_vector_type(8))) short short8;
typedef __attribute__((ext_vector_type(4))) float f32x4;

static __device__ __forceinline__ unsigned f2bf(float f) {
    unsigned u = __float_as_uint(f);
    unsigned r = u + 0x7fffu + ((u >> 16) & 1u);   // RNE
    return r >> 16;
}
static __device__ __forceinline__ float bf2f(unsigned short b) {
    return __uint_as_float(((unsigned)b) << 16);
}

// ---------------- Kernel 0: Wb = bf16(W) [blocks 0..2047]; wt8 [blocks 2048..2055] ----------
__global__ __launch_bounds__(256) void prep_w_kernel(
    const float* __restrict__ W, const float* __restrict__ a,
    unsigned short* __restrict__ Wb, float* __restrict__ wt8)
{
    if (blockIdx.x < 2048) {
        const int id = blockIdx.x * 256 + threadIdx.x;
        Wb[id] = (unsigned short)f2bf(W[id]);
        return;
    }
    const int v = blockIdx.x - 2048;    // 0..7
    const int k = v >> 1, s = v & 1;
    const int i = threadIdx.x;          // 0..255
    const float* av = a + k * 2 * OUT_DIM + s * OUT_DIM;
    float acc = 0.f;
    #pragma unroll 4
    for (int o = 0; o < OUT_DIM; ++o)
        acc += W[((size_t)k * OUT_DIM + o) * IN_DIM + i] * av[o];
    wt8[v * IN_DIM + i] = acc;
}

// ---------------- Kernel 1: prep — Xb = bf16(X); e4 layouts [n][4] (heads adjacent) --------
__global__ __launch_bounds__(256) void prep_kernel(
    const float* __restrict__ X, const float* __restrict__ wt8,
    unsigned short* __restrict__ Xb, float* __restrict__ e_nb4, float* __restrict__ e_self4)
{
    const int t = threadIdx.x;
    const int w = t >> 6;
    const int lane = t & 63;
    const int n = blockIdx.x * 4 + w;

    const f32x4 x = __builtin_nontemporal_load(
        (const f32x4*)(X + (size_t)n * IN_DIM + lane * 4));
    uint2 pk;
    pk.x = f2bf(x[0]) | (f2bf(x[1]) << 16);
    pk.y = f2bf(x[2]) | (f2bf(x[3]) << 16);
    *(uint2*)(Xb + (size_t)n * IN_DIM + lane * 4) = pk;

    float p[8];
    #pragma unroll
    for (int v = 0; v < 8; ++v) {
        const float4 wv = *(const float4*)(wt8 + v * IN_DIM + lane * 4);
        p[v] = x[0] * wv.x + x[1] * wv.y + x[2] * wv.z + x[3] * wv.w;
    }
    #pragma unroll
    for (int sh = 32; sh >= 1; sh >>= 1) {
        #pragma unroll
        for (int v = 0; v < 8; ++v) p[v] += __shfl_xor(p[v], sh);
    }
    if (lane == 0) {
        *(float4*)(e_nb4 + (size_t)n * 4)   = float4{p[0], p[2], p[4], p[6]};
        *(float4*)(e_self4 + (size_t)n * 4) = float4{p[1], p[3], p[5], p[7]};
    }
}

// ---------------- Kernel 2: fused alpha + X-gather aggregation (uint2 form — agg floor) ----
// Wave = 1 node; e gathers coalesced via [n][4] float4; Xb rows gathered 512 B contiguous
// per instruction (uint2 = 8 B/lane); accumulates all 4 heads. 36 VGPR -> ~61% occupancy.
__global__ __launch_bounds__(256) void agg_kernel(
    const int* __restrict__ nidx, const unsigned short* __restrict__ Xb,
    const float* __restrict__ e_nb4, const float* __restrict__ e_self4,
    unsigned short* __restrict__ aggX, int n0, int nc)
{
    const int t = threadIdx.x;
    const int w = t >> 6;
    const int lane = t & 63;
    const int n = n0 + blockIdx.x * 4 + w;
    if (n >= n0 + nc || n >= N_NODES) return;

    const int k = lane >> 4;
    const int dl = lane & 15;

    const int nbr = __builtin_nontemporal_load(nidx + (size_t)n * D_NB + dl);
    const float4 eb4 = *(const float4*)(e_nb4 + (size_t)nbr * 4);
    const float4 es4 = *(const float4*)(e_self4 + (size_t)n * 4);
    const float en = (k & 2) ? ((k & 1) ? eb4.w : eb4.z) : ((k & 1) ? eb4.y : eb4.x);
    const float es = (k & 2) ? ((k & 1) ? es4.w : es4.z) : ((k & 1) ? es4.y : es4.x);
    const float xv = en + es;
    const float v = xv > 0.f ? xv : SLOPE * xv;
    float m = v;
    #pragma unroll
    for (int sh = 8; sh >= 1; sh >>= 1) m = fmaxf(m, __shfl_xor(m, sh, 16));
    const float pz = __expf(v - m);
    float sum = pz;
    #pragma unroll
    for (int sh = 8; sh >= 1; sh >>= 1) sum += __shfl_xor(sum, sh, 16);
    const float alpha = pz / sum;

    float acc[4][4] = {};
    #pragma unroll
    for (int h = 0; h < 2; ++h) {
        uint2 u[8];
        #pragma unroll
        for (int b = 0; b < 8; ++b) {
            const int nd = __shfl(nbr, h * 8 + b);
            u[b] = *(const uint2*)(Xb + (size_t)nd * IN_DIM + lane * 4);
        }
        #pragma unroll
        for (int b = 0; b < 8; ++b) {
            const float x0 = bf2f((unsigned short)(u[b].x & 0xffffu));
            const float x1 = bf2f((unsigned short)(u[b].x >> 16));
            const float x2 = bf2f((unsigned short)(u[b].y & 0xffffu));
            const float x3 = bf2f((unsigned short)(u[b].y >> 16));
            #pragma unroll
            for (int kk = 0; kk < 4; ++kk) {
                const float ad = __shfl(alpha, kk * 16 + h * 8 + b);
                acc[kk][0] += ad * x0;
                acc[kk][1] += ad * x1;
                acc[kk][2] += ad * x2;
                acc[kk][3] += ad * x3;
            }
        }
    }
    #pragma unroll
    for (int kk = 0; kk < 4; ++kk) {
        uint2 pk;
        pk.x = f2bf(acc[kk][0]) | (f2bf(acc[kk][1]) << 16);
        pk.y = f2bf(acc[kk][2]) | (f2bf(acc[kk][3]) << 16);
        *(uint2*)(aggX + ((size_t)kk * nc + (n - n0)) * IN_DIM + lane * 4) = pk;
    }
}

// ---------------- Kernel 3: GEMM2 — out[n][k*128+o] = aggX[k][n]·W[k][o] (MFMA) ------------
// 512 threads / 8 waves, 128 rows/block, fully unrolled 16-stage loop with ping-pong af
// prefetch (next head's A issued one stage early). Out stores cached.
__global__ __launch_bounds__(512) void gemm2_kernel(
    const unsigned short* __restrict__ aggX, const unsigned short* __restrict__ Wb,
    float* __restrict__ out, int n0, int nc)
{
    __shared__ unsigned short Wlds[2][SLICE_COLS * IN_DIM];   // 2 x 16 KB

    const int t = threadIdx.x;
    const int lane = t & 63;
    const int w = t >> 6;           // 0..7
    const int lrow = lane & 15;
    const int lk = lane >> 4;
    const int m0 = n0 + blockIdx.x * 128 + w * 16;

    const int arow = m0 + lrow;
    const bool avalid = (arow < n0 + nc) && (arow < N_NODES);

    auto STAGE = [&](int st, int buf) {
        const unsigned short* WbS = Wb + (size_t)st * SLICE_COLS * IN_DIM;
        #pragma unroll
        for (int i = 0; i < 2; ++i) {
            const int c = i * 512 + t;       // 1024 chunks, 2 per thread
            const int r = c >> 5;
            const int p = c & 31;
            const int cu = p ^ (r & 7);
            const unsigned short* gsrc = WbS + r * IN_DIM + cu * 8;
            unsigned short* ldst = &Wlds[buf][c * 8];
            __builtin_amdgcn_global_load_lds(
                (const __attribute__((address_space(1))) void*)gsrc,
                (__attribute__((address_space(3))) void*)ldst, 16, 0, 0);
        }
    };

    short8 af[2][8];
    auto LOADAF = [&](int head, int slot) {
        const unsigned short* Ar = aggX + ((size_t)head * nc + (arow - n0)) * IN_DIM + lk * 8;
        #pragma unroll
        for (int kk = 0; kk < 8; ++kk)
            af[slot][kk] = avalid ? *(const short8*)(Ar + kk * 32)
                                  : short8{0, 0, 0, 0, 0, 0, 0, 0};
    };

    STAGE(0, 0);
    LOADAF(0, 0);
    __syncthreads();

    #pragma unroll
    for (int st = 0; st < NSLICE; ++st) {
        const int buf = st & 1;
        if (st + 1 < NSLICE) STAGE(st + 1, buf ^ 1);
        if ((st & 3) == 3 && st + 1 < NSLICE)
            LOADAF((st >> 2) + 1, ((st >> 2) + 1) & 1);   // prefetch next head's A

        const int slot = (st >> 2) & 1;
        f32x4 acc[2] = {};
        #pragma unroll
        for (int kk = 0; kk < 8; ++kk) {
            #pragma unroll
            for (int nt = 0; nt < 2; ++nt) {
                const int row = nt * 16 + lrow;
                const int pos = (kk * 4 + lk) ^ (row & 7);
                const short8 bf = *(const short8*)(&Wlds[buf][row * IN_DIM + pos * 8]);
                acc[nt] = __builtin_amdgcn_mfma_f32_16x16x32_bf16(bf, af[slot][kk], acc[nt], 0, 0, 0);
            }
        }

        const int k = st >> 2, cb = st & 3;
        if (avalid) {
            const size_t cbase = (size_t)arow * (K_HEADS * OUT_DIM)
                               + (size_t)k * OUT_DIM + cb * SLICE_COLS + lk * 4;
            #pragma unroll
            for (int nt = 0; nt < 2; ++nt)
                *(f32x4*)(out + cbase + nt * 16) = acc[nt];
        }
        __syncthreads();
    }
}

// ---------------- launch ----------------
extern "C" void kernel_launch(void* const* d_in, const int* in_sizes, int n_in,
                              void* d_out, int out_size, void* d_ws, size_t ws_size,
                              hipStream_t stream) {
    const float* X = (const float*)d_in[0];
    const float* W = (const float*)d_in[1];
    const float* a = (const float*)d_in[2];
    const int* nidx = (const int*)d_in[3];
    float* out = (float*)d_out;

    const size_t WbB  = (size_t)K_HEADS * OUT_DIM * IN_DIM * 2;
    const size_t XbB  = (size_t)N_NODES * IN_DIM * 2;
    const size_t wt8B = (size_t)8 * IN_DIM * 4;
    const size_t eB   = (size_t)K_HEADS * N_NODES * 4;
    auto need = [&](int nc) {
        return WbB + XbB + wt8B + 2 * eB + (size_t)K_HEADS * nc * IN_DIM * 2 + 1024;
    };

    int np, nc;
    if      (ws_size >= need(50000)) { np = 1; nc = 50000; }
    else if (ws_size >= need(25000)) { np = 2; nc = 25000; }
    else                             { np = 4; nc = 12500; }

    char* p = (char*)d_ws;
    unsigned short* Wb   = (unsigned short*)p;   p += WbB;
    unsigned short* Xb   = (unsigned short*)p;   p += XbB;
    float*          wt8  = (float*)p;            p += wt8B;
    float*          enb4 = (float*)p;            p += eB;
    float*          esf4 = (float*)p;            p += eB;
    unsigned short* aggX = (unsigned short*)p;

    hipLaunchKernelGGL(prep_w_kernel, dim3(2056), dim3(256), 0, stream, W, a, Wb, wt8);

    hipLaunchKernelGGL(prep_kernel,
        dim3(N_NODES / 4), dim3(256), 0, stream, X, wt8, Xb, enb4, esf4);

    for (int pass = 0; pass < np; ++pass) {
        const int nb0 = pass * nc;
        hipLaunchKernelGGL(agg_kernel,
            dim3((nc + 3) / 4), dim3(256), 0, stream, nidx, Xb, enb4, esf4, aggX, nb0, nc);
        hipLaunchKernelGGL(gemm2_kernel,
            dim3((nc + 127) / 128), dim3(512), 0, stream, aggX, Wb, out, nb0, nc);
    }
}